// Round 3
// baseline (249.450 us; speedup 1.0000x reference)
//
#include <hip/hip_runtime.h>
#include <math.h>

#define BB 8
#define NN 2000
#define CC 81
#define MAXI 100
#define WPB 32              // 64-bit words per bitmask row (2048 bits >= 2000)

static constexpr float kMinConf = 0.7f;
static constexpr float kNmsThr  = 0.3f;

// ---------------- workspace layout (bytes) ----------------
// boxes  : [0,       256000)   BN*4 f32
// key    : [256000,  320000)   BN f32  (score if valid else -inf)
// cls    : [320000,  384000)   BN i32
// sboxes : [384000,  640000)   BN*4 f32 (sorted)
// sscore : [640000,  704000)   BN f32   (sorted key)
// scls   : [704000,  768000)   BN i32   (sorted)
// vbits  : [768000,  770048)   B*32 u64 (valid bitmask in sorted order)
// supT   : [770048,  4866048)  B*32*2000 u64, word-major transposed suppression:
//          supT[(b*32+v)*NN + j] bit i = "row v*64+i suppresses row j" (v*64+i < j)

// ---- k1: wave-per-ROI argmax + box refine (coalesced probs reads) ----
__global__ void k1_refine(const float* __restrict__ rois,
                          const float* __restrict__ probs,
                          const float* __restrict__ deltas,
                          float* __restrict__ boxes,
                          float* __restrict__ key,
                          int* __restrict__ cls,
                          unsigned long long* __restrict__ vbits) {
    if (blockIdx.x == 0) vbits[threadIdx.x] = 0ull;   // 256 threads == BB*WPB words

    int gtid = blockIdx.x * blockDim.x + threadIdx.x;
    int wid = gtid >> 6;                // one wave per ROI
    int l = gtid & 63;
    if (wid >= BB * NN) return;

    const float* p = probs + (size_t)wid * CC;
    float v1 = p[l];                    // l in [0,64) < 81 always valid
    int   i1 = l;
    int   c2 = l + 64;
    float v2 = (c2 < CC) ? p[c2] : -1.0f;   // probs are in [0,1)
    float bv; int bi;
    if (v2 > v1) { bv = v2; bi = c2; } else { bv = v1; bi = i1; }

    #pragma unroll
    for (int off = 32; off; off >>= 1) {
        float ov = __shfl_xor(bv, off);
        int   oi = __shfl_xor(bi, off);
        if (ov > bv || (ov == bv && oi < bi)) { bv = ov; bi = oi; }
    }
    // all lanes now agree: bi = first argmax, bv = max score

    if (l == 0) {
        const float4 dl = *(const float4*)(deltas + ((size_t)wid * CC + bi) * 4);
        float dy = dl.x * 0.1f, dx = dl.y * 0.1f, dh = dl.z * 0.2f, dw = dl.w * 0.2f;
        const float4 r = *(const float4*)(rois + (size_t)wid * 4);
        float y1 = r.x, x1 = r.y, y2 = r.z, x2 = r.w;
        float h = y2 - y1, w = x2 - x1;
        float cy = y1 + 0.5f * h + dy * h;
        float cx = x1 + 0.5f * w + dx * w;
        float h2 = h * expf(dh);
        float w2 = w * expf(dw);
        float oy1 = fminf(fmaxf(cy - 0.5f * h2, 0.f), 1.f);
        float ox1 = fminf(fmaxf(cx - 0.5f * w2, 0.f), 1.f);
        float oy2 = fminf(fmaxf(cy + 0.5f * h2, 0.f), 1.f);
        float ox2 = fminf(fmaxf(cx + 0.5f * w2, 0.f), 1.f);
        bool valid = (bi > 0) && (bv >= kMinConf);
        float4 bx; bx.x = oy1; bx.y = ox1; bx.z = oy2; bx.w = ox2;
        ((float4*)boxes)[wid] = bx;
        key[wid] = valid ? bv : -INFINITY;
        cls[wid] = bi;
    }
}

// ---- k2: O(N^2) rank sort (unchanged) ----
__global__ void k2_rank(const float* __restrict__ boxes,
                        const float* __restrict__ key,
                        const int* __restrict__ cls,
                        float* __restrict__ sboxes,
                        float* __restrict__ sscore,
                        int* __restrict__ scls,
                        unsigned long long* __restrict__ vbits) {
    int idx = blockIdx.x * blockDim.x + threadIdx.x;
    if (idx >= BB * NN) return;
    int b = idx / NN, i = idx - b * NN;
    const float* kb = key + (size_t)b * NN;
    float ki = kb[i];
    int rank = 0;
    const float4* k4 = (const float4*)kb;
    for (int j4 = 0; j4 < NN / 4; ++j4) {
        float4 kv = k4[j4];
        int j = j4 * 4;
        rank += (kv.x > ki) || (kv.x == ki && (j + 0) < i);
        rank += (kv.y > ki) || (kv.y == ki && (j + 1) < i);
        rank += (kv.z > ki) || (kv.z == ki && (j + 2) < i);
        rank += (kv.w > ki) || (kv.w == ki && (j + 3) < i);
    }
    int dst = b * NN + rank;
    ((float4*)sboxes)[dst] = ((const float4*)boxes)[idx];
    sscore[dst] = ki;
    scls[dst] = cls[idx];
    if (ki != -INFINITY) {
        atomicOr(&vbits[b * WPB + (rank >> 6)], 1ull << (rank & 63));
    }
}

// ---- k3: transposed suppression matrix, word-major [b][v][j] ----
// thread -> (b, v, j) with j fastest: writes coalesced, inner gi loads wave-uniform
__global__ void k3_supT(const float* __restrict__ sboxes,
                        const int* __restrict__ scls,
                        unsigned long long* __restrict__ supT) {
    int idx = blockIdx.x * blockDim.x + threadIdx.x;
    if (idx >= BB * WPB * NN) return;
    int j = idx % NN;
    int v = (idx / NN) & 31;
    int b = idx / (NN * WPB);
    int i0 = v * 64;
    size_t oidx = (size_t)(b * WPB + v) * NN + j;
    if (i0 >= j) { supT[oidx] = 0ull; return; }      // suppressors must be earlier rows

    const float4* bxs = (const float4*)sboxes + (size_t)b * NN;
    const int* cl = scls + (size_t)b * NN;
    float4 a = bxs[j];
    int cj = cl[j];
    float aarea = (a.z - a.x) * (a.w - a.y);

    unsigned long long m = 0ull;
    int iend = min(i0 + 64, j);
    for (int gi = i0; gi < iend; ++gi) {
        if (cl[gi] != cj) continue;                   // cl[gi] wave-uniform
        float4 bj = bxs[gi];
        float iy1 = fmaxf(a.x, bj.x), ix1 = fmaxf(a.y, bj.y);
        float iy2 = fminf(a.z, bj.z), ix2 = fminf(a.w, bj.w);
        float inter = fmaxf(iy2 - iy1, 0.f) * fmaxf(ix2 - ix1, 0.f);
        float barea = (bj.z - bj.x) * (bj.w - bj.y);
        float uni = fmaxf(aarea + barea - inter, 1e-12f);
        if (inter > kNmsThr * uni) m |= (1ull << (gi - i0));
    }
    supT[oidx] = m;
}

__device__ __forceinline__ unsigned long long readlane_u64(unsigned long long v, int lane) {
    unsigned int lo = (unsigned int)(v & 0xffffffffull);
    unsigned int hi = (unsigned int)(v >> 32);
    lo = (unsigned int)__builtin_amdgcn_readlane((int)lo, lane);
    hi = (unsigned int)__builtin_amdgcn_readlane((int)hi, lane);
    return ((unsigned long long)hi << 32) | (unsigned long long)lo;
}

// ---- k4: blocked greedy NMS via wave-wide ballot fixpoint ----
// 32 word-blocks; per block: coalesced gather of suppressor words vs resolved
// earlier kept-words, then 64x64 diagonal resolve by iterated ballot (provably
// converges to the greedy solution: unique fixpoint, levels stabilize).
__global__ void __launch_bounds__(64) k4_scan(const unsigned long long* __restrict__ supT,
                        const unsigned long long* __restrict__ vbits,
                        const float* __restrict__ sboxes,
                        const float* __restrict__ sscore,
                        const int* __restrict__ scls,
                        float* __restrict__ out) {
    const int b = blockIdx.x;
    const int l = threadIdx.x;          // 0..63
    const unsigned long long* st = supT + (size_t)b * WPB * NN;

    unsigned long long keptdist = 0ull; // lane v holds final kept word v (v<32)

    for (int w = 0; w < WPB; ++w) {
        int row = w * 64 + l;
        int rowc = (row < NN) ? row : (NN - 1);      // clamp for safe loads
        unsigned long long colmask = st[(size_t)w * NN + rowc];   // coalesced
        unsigned long long acc = 0ull;
        for (int v = 0; v < w; ++v) {
            unsigned long long km = readlane_u64(keptdist, v);    // uniform
            acc |= st[(size_t)v * NN + rowc] & km;                // coalesced
        }
        unsigned long long vw = vbits[b * WPB + w];               // uniform
        bool pre = ((vw >> l) & 1ull) && (acc == 0ull) && (row < NN);

        unsigned long long kept = __ballot(pre);
        while (true) {
            bool alive = pre && ((colmask & kept) == 0ull);
            unsigned long long k2 = __ballot(alive);
            if (k2 == kept) break;
            kept = k2;
        }
        if (l == w) keptdist = kept;
    }

    // ---- emit first 100 kept in order ----
    int cnt = __popcll(keptdist);
    int base = 0, total = 0;
    for (int w2 = 0; w2 < 32; ++w2) {
        int c2 = __shfl(cnt, w2);
        if (w2 < l) base += c2;
        total += c2;
    }

    if (l < 32) {
        unsigned long long kk = keptdist;
        int r = base;
        while (kk) {
            int k = __builtin_ctzll(kk);
            kk &= kk - 1;
            if (r < MAXI) {
                int j = l * 64 + k;
                float4 bx = ((const float4*)sboxes)[b * NN + j];
                float* o = out + ((size_t)b * MAXI + r) * 6;
                o[0] = bx.x; o[1] = bx.y; o[2] = bx.z; o[3] = bx.w;
                o[4] = (float)scls[b * NN + j];
                o[5] = sscore[b * NN + j];
            }
            ++r;
        }
    }
    for (int r = total + l; r < MAXI; r += 64) {
        float* o = out + ((size_t)b * MAXI + r) * 6;
        #pragma unroll
        for (int q = 0; q < 6; ++q) o[q] = 0.f;
    }
}

extern "C" void kernel_launch(void* const* d_in, const int* in_sizes, int n_in,
                              void* d_out, int out_size, void* d_ws, size_t ws_size,
                              hipStream_t stream) {
    const float* rois   = (const float*)d_in[0];
    const float* probs  = (const float*)d_in[1];
    const float* deltas = (const float*)d_in[2];
    float* out = (float*)d_out;

    char* ws = (char*)d_ws;
    float* boxes  = (float*)(ws + 0);
    float* key    = (float*)(ws + 256000);
    int*   cls    = (int*)  (ws + 320000);
    float* sboxes = (float*)(ws + 384000);
    float* sscore = (float*)(ws + 640000);
    int*   scls   = (int*)  (ws + 704000);
    unsigned long long* vbits = (unsigned long long*)(ws + 768000);
    unsigned long long* supT  = (unsigned long long*)(ws + 770048);

    {
        // one wave per ROI: BB*NN waves, 256-thread blocks (4 waves each)
        int blocks = (BB * NN * 64) / 256;   // 4000, exact
        k1_refine<<<blocks, 256, 0, stream>>>(rois, probs, deltas, boxes, key, cls, vbits);
    }
    {
        int threads = BB * NN;
        int blocks = (threads + 255) / 256;
        k2_rank<<<blocks, 256, 0, stream>>>(boxes, key, cls, sboxes, sscore, scls, vbits);
    }
    {
        int threads = BB * WPB * NN;
        int blocks = (threads + 255) / 256;
        k3_supT<<<blocks, 256, 0, stream>>>(sboxes, scls, supT);
    }
    {
        k4_scan<<<BB, 64, 0, stream>>>(supT, vbits, sboxes, sscore, scls, out);
    }
}

// Round 4
// 102.372 us; speedup vs baseline: 2.4367x; 2.4367x over previous
//
#include <hip/hip_runtime.h>
#include <math.h>

#define BB 8
#define NN 2000
#define CC 81
#define MAXI 100
#define WPB 32              // 64-bit words per kept-bitmask (2048 bits >= 2000)

static constexpr float kMinConf = 0.7f;
static constexpr float kNmsThr  = 0.3f;

// ---------------- workspace layout (bytes) ----------------
// boxes  : [0,       256000)   BN*4 f32
// key    : [256000,  320000)   BN f32  (score if valid else -inf)
// cls    : [320000,  384000)   BN i32
// sboxes : [384000,  640000)   BN*4 f32 (sorted)
// sscore : [640000,  704000)   BN f32   (sorted key)
// scls   : [704000,  768000)   BN i32   (sorted)
// kw     : [768000,  770048)   B*32 u64 kept bits in sorted order (zeroed in k1)

// ---- k1: wave-per-ROI argmax + box refine (coalesced probs reads) ----
__global__ void k1_refine(const float* __restrict__ rois,
                          const float* __restrict__ probs,
                          const float* __restrict__ deltas,
                          float* __restrict__ boxes,
                          float* __restrict__ key,
                          int* __restrict__ cls,
                          unsigned long long* __restrict__ kw) {
    if (blockIdx.x == 0) kw[threadIdx.x] = 0ull;      // 256 threads == BB*WPB words

    int gtid = blockIdx.x * blockDim.x + threadIdx.x;
    int wid = gtid >> 6;                // one wave per ROI
    int l = gtid & 63;
    if (wid >= BB * NN) return;

    const float* p = probs + (size_t)wid * CC;
    float v1 = p[l];                    // l in [0,64) < 81 always valid
    int   i1 = l;
    int   c2 = l + 64;
    float v2 = (c2 < CC) ? p[c2] : -1.0f;   // probs in [0,1)
    float bv; int bi;
    if (v2 > v1) { bv = v2; bi = c2; } else { bv = v1; bi = i1; }

    #pragma unroll
    for (int off = 32; off; off >>= 1) {
        float ov = __shfl_xor(bv, off);
        int   oi = __shfl_xor(bi, off);
        if (ov > bv || (ov == bv && oi < bi)) { bv = ov; bi = oi; }
    }

    if (l == 0) {
        const float4 dl = *(const float4*)(deltas + ((size_t)wid * CC + bi) * 4);
        float dy = dl.x * 0.1f, dx = dl.y * 0.1f, dh = dl.z * 0.2f, dw = dl.w * 0.2f;
        const float4 r = *(const float4*)(rois + (size_t)wid * 4);
        float y1 = r.x, x1 = r.y, y2 = r.z, x2 = r.w;
        float h = y2 - y1, w = x2 - x1;
        float cy = y1 + 0.5f * h + dy * h;
        float cx = x1 + 0.5f * w + dx * w;
        float h2 = h * expf(dh);
        float w2 = w * expf(dw);
        float oy1 = fminf(fmaxf(cy - 0.5f * h2, 0.f), 1.f);
        float ox1 = fminf(fmaxf(cx - 0.5f * w2, 0.f), 1.f);
        float oy2 = fminf(fmaxf(cy + 0.5f * h2, 0.f), 1.f);
        float ox2 = fminf(fmaxf(cx + 0.5f * w2, 0.f), 1.f);
        bool valid = (bi > 0) && (bv >= kMinConf);
        float4 bx; bx.x = oy1; bx.y = ox1; bx.z = oy2; bx.w = ox2;
        ((float4*)boxes)[wid] = bx;
        key[wid] = valid ? bv : -INFINITY;
        cls[wid] = bi;
    }
}

// ---- k2: O(N^2) rank sort ----
__global__ void k2_rank(const float* __restrict__ boxes,
                        const float* __restrict__ key,
                        const int* __restrict__ cls,
                        float* __restrict__ sboxes,
                        float* __restrict__ sscore,
                        int* __restrict__ scls) {
    int idx = blockIdx.x * blockDim.x + threadIdx.x;
    if (idx >= BB * NN) return;
    int b = idx / NN, i = idx - b * NN;
    const float* kb = key + (size_t)b * NN;
    float ki = kb[i];
    int rank = 0;
    const float4* k4 = (const float4*)kb;
    for (int j4 = 0; j4 < NN / 4; ++j4) {
        float4 kv = k4[j4];
        int j = j4 * 4;
        rank += (kv.x > ki) || (kv.x == ki && (j + 0) < i);
        rank += (kv.y > ki) || (kv.y == ki && (j + 1) < i);
        rank += (kv.z > ki) || (kv.z == ki && (j + 2) < i);
        rank += (kv.w > ki) || (kv.w == ki && (j + 3) < i);
    }
    int dst = b * NN + rank;
    ((float4*)sboxes)[dst] = ((const float4*)boxes)[idx];
    sscore[dst] = ki;
    scls[dst] = cls[idx];
}

__device__ __forceinline__ float iou_gt_thr(float4 a, float aarea, float4 t) {
    float iy1 = fmaxf(a.x, t.x), ix1 = fmaxf(a.y, t.y);
    float iy2 = fminf(a.z, t.z), ix2 = fminf(a.w, t.w);
    float inter = fmaxf(iy2 - iy1, 0.f) * fmaxf(ix2 - ix1, 0.f);
    float tarea = (t.z - t.x) * (t.w - t.y);
    float uni = fmaxf(aarea + tarea - inter, 1e-12f);
    return (inter > kNmsThr * uni) ? 1.f : 0.f;
}

// ---- k3: per-(batch,class) greedy NMS. Class-aware NMS decomposes exactly:
// keep decisions never cross classes, so greedy on the global order restricted
// to class c == greedy NMS on class c's members in score order. ~25 members
// per class -> one 64-wide ballot fixpoint (validated exact in prior rounds).
__global__ void __launch_bounds__(64) k3_classnms(const float* __restrict__ sboxes,
                          const float* __restrict__ sscore,
                          const int* __restrict__ scls,
                          unsigned long long* __restrict__ kw) {
    const int blk = blockIdx.x;
    const int b = blk / (CC - 1);
    const int c = blk % (CC - 1) + 1;      // classes 1..80 (class 0 never valid)
    const int l = threadIdx.x;

    const float4* bxs = (const float4*)sboxes + (size_t)b * NN;
    const float* ss = sscore + (size_t)b * NN;
    const int* cl = scls + (size_t)b * NN;

    __shared__ int    midx[NN];
    __shared__ float4 mbox[NN];
    __shared__ unsigned char mkept[NN];

    // ---- scan sorted rows, collect members of class c (double-buffered) ----
    int cnt = 0;
    int i_cur = l;
    float sc_cur = ss[i_cur];
    int   cl_cur = cl[i_cur];
    constexpr int NCH = (NN + 63) / 64;    // 32 chunks (last partial)
    for (int ch = 0; ch < NCH; ++ch) {
        int i_nxt = (ch + 1) * 64 + l;
        float sc_nxt = 0.f; int cl_nxt = -1;
        if (ch + 1 < NCH && i_nxt < NN) { sc_nxt = ss[i_nxt]; cl_nxt = cl[i_nxt]; }
        int i = ch * 64 + l;
        bool pred = (i < NN) && (cl_cur == c) && (sc_cur != -INFINITY);
        unsigned long long mask = __ballot(pred);
        if (pred) {
            int pos = cnt + __popcll(mask & ((1ull << l) - 1ull));
            midx[pos] = i;
            mbox[pos] = bxs[i];
        }
        cnt += __popcll(mask);
        sc_cur = sc_nxt; cl_cur = cl_nxt;
    }
    __syncthreads();

    // ---- greedy NMS over members, 64 at a time ----
    for (int q0 = 0; q0 < cnt; q0 += 64) {
        int m = q0 + l;
        bool active = (m < cnt);
        float4 a = mbox[active ? m : 0];
        float aarea = (a.z - a.x) * (a.w - a.y);

        // suppression by earlier chunks' kept members (rare: cnt>64)
        bool presup = false;
        for (int t = 0; t < q0; ++t) {
            if (mkept[t] && iou_gt_thr(a, aarea, mbox[t]) != 0.f) presup = true;
        }

        // diagonal 64x64 colmask: earlier members in this chunk that suppress me
        unsigned long long colmask = 0ull;
        int tend = min(64, cnt - q0);
        for (int t = 0; t < tend; ++t) {
            float4 tb = mbox[q0 + t];                 // wave-uniform LDS broadcast
            if (t < l && iou_gt_thr(a, aarea, tb) != 0.f) colmask |= (1ull << t);
        }

        bool pre = active && !presup;
        unsigned long long kept = __ballot(pre);
        while (true) {
            bool alive0 = pre && ((colmask & kept) == 0ull);
            unsigned long long k2m = __ballot(alive0);
            if (k2m == kept) break;
            kept = k2m;
        }
        bool alive = pre && ((colmask & kept) == 0ull);
        if (active) {
            mkept[m] = alive ? 1 : 0;
            if (alive) {
                int j = midx[m];
                atomicOr(&kw[b * WPB + (j >> 6)], 1ull << (j & 63));
            }
        }
        __syncthreads();
    }
}

// ---- k4: emit first 100 kept rows in sorted order ----
__global__ void __launch_bounds__(64) k4_emit(const unsigned long long* __restrict__ kw,
                        const float* __restrict__ sboxes,
                        const float* __restrict__ sscore,
                        const int* __restrict__ scls,
                        float* __restrict__ out) {
    const int b = blockIdx.x;
    const int l = threadIdx.x;

    unsigned long long keep = (l < WPB) ? kw[b * WPB + l] : 0ull;

    int cnt = __popcll(keep);
    int base = 0, total = 0;
    for (int w2 = 0; w2 < 32; ++w2) {
        int c2 = __shfl(cnt, w2);
        if (w2 < l) base += c2;
        total += c2;
    }

    if (l < 32) {
        unsigned long long kk = keep;
        int r = base;
        while (kk) {
            int k = __builtin_ctzll(kk);
            kk &= kk - 1;
            if (r < MAXI) {
                int j = l * 64 + k;
                float4 bx = ((const float4*)sboxes)[b * NN + j];
                float* o = out + ((size_t)b * MAXI + r) * 6;
                o[0] = bx.x; o[1] = bx.y; o[2] = bx.z; o[3] = bx.w;
                o[4] = (float)scls[b * NN + j];
                o[5] = sscore[b * NN + j];
            }
            ++r;
        }
    }
    for (int r = total + l; r < MAXI; r += 64) {
        float* o = out + ((size_t)b * MAXI + r) * 6;
        #pragma unroll
        for (int q = 0; q < 6; ++q) o[q] = 0.f;
    }
}

extern "C" void kernel_launch(void* const* d_in, const int* in_sizes, int n_in,
                              void* d_out, int out_size, void* d_ws, size_t ws_size,
                              hipStream_t stream) {
    const float* rois   = (const float*)d_in[0];
    const float* probs  = (const float*)d_in[1];
    const float* deltas = (const float*)d_in[2];
    float* out = (float*)d_out;

    char* ws = (char*)d_ws;
    float* boxes  = (float*)(ws + 0);
    float* key    = (float*)(ws + 256000);
    int*   cls    = (int*)  (ws + 320000);
    float* sboxes = (float*)(ws + 384000);
    float* sscore = (float*)(ws + 640000);
    int*   scls   = (int*)  (ws + 704000);
    unsigned long long* kw = (unsigned long long*)(ws + 768000);

    {
        int blocks = (BB * NN * 64) / 256;   // one wave per ROI
        k1_refine<<<blocks, 256, 0, stream>>>(rois, probs, deltas, boxes, key, cls, kw);
    }
    {
        int threads = BB * NN;
        int blocks = (threads + 255) / 256;
        k2_rank<<<blocks, 256, 0, stream>>>(boxes, key, cls, sboxes, sscore, scls);
    }
    {
        k3_classnms<<<BB * (CC - 1), 64, 0, stream>>>(sboxes, sscore, scls, kw);
    }
    {
        k4_emit<<<BB, 64, 0, stream>>>(kw, sboxes, sscore, scls, out);
    }
}

// Round 5
// 49.859 us; speedup vs baseline: 5.0031x; 2.0532x over previous
//
#include <hip/hip_runtime.h>
#include <math.h>

#define BB 8
#define NN 2000
#define CC 81
#define MAXI 100
#define WPB 32              // 64-bit words per kept-bitmask (2048 bits >= 2000)

static constexpr float kMinConf = 0.7f;
static constexpr float kNmsThr  = 0.3f;

// ---------------- workspace layout (bytes) ----------------
// boxes  : [0,       256000)   BN*4 f32
// key    : [256000,  320000)   BN f32  (score if valid else -inf)
// cls    : [320000,  384000)   BN i32
// sboxes : [384000,  640000)   BN*4 f32 (sorted)
// sscore : [640000,  704000)   BN f32   (sorted key)
// scls   : [704000,  768000)   BN i32   (sorted)
// kw     : [768000,  770048)   B*32 u64 kept bits in sorted order (zeroed in k1)
// ckey   : [770048,  898048)   BN u64 composite sort key (16B-aligned)

__device__ __forceinline__ unsigned int mono_u32(float f) {
    unsigned int u = __float_as_uint(f);
    return (u & 0x80000000u) ? ~u : (u | 0x80000000u);   // order-preserving
}

// ---- k1: wave-per-ROI argmax + box refine (coalesced probs reads) ----
__global__ void k1_refine(const float* __restrict__ rois,
                          const float* __restrict__ probs,
                          const float* __restrict__ deltas,
                          float* __restrict__ boxes,
                          float* __restrict__ key,
                          int* __restrict__ cls,
                          unsigned long long* __restrict__ ckey,
                          unsigned long long* __restrict__ kw) {
    if (blockIdx.x == 0) kw[threadIdx.x] = 0ull;      // 256 threads == BB*WPB words

    int gtid = blockIdx.x * blockDim.x + threadIdx.x;
    int wid = gtid >> 6;                // one wave per ROI
    int l = gtid & 63;
    if (wid >= BB * NN) return;

    const float* p = probs + (size_t)wid * CC;
    float v1 = p[l];                    // l in [0,64) < 81 always valid
    int   i1 = l;
    int   c2 = l + 64;
    float v2 = (c2 < CC) ? p[c2] : -1.0f;   // probs in [0,1)
    float bv; int bi;
    if (v2 > v1) { bv = v2; bi = c2; } else { bv = v1; bi = i1; }

    #pragma unroll
    for (int off = 32; off; off >>= 1) {
        float ov = __shfl_xor(bv, off);
        int   oi = __shfl_xor(bi, off);
        if (ov > bv || (ov == bv && oi < bi)) { bv = ov; bi = oi; }
    }

    if (l == 0) {
        const float4 dl = *(const float4*)(deltas + ((size_t)wid * CC + bi) * 4);
        float dy = dl.x * 0.1f, dx = dl.y * 0.1f, dh = dl.z * 0.2f, dw = dl.w * 0.2f;
        const float4 r = *(const float4*)(rois + (size_t)wid * 4);
        float y1 = r.x, x1 = r.y, y2 = r.z, x2 = r.w;
        float h = y2 - y1, w = x2 - x1;
        float cy = y1 + 0.5f * h + dy * h;
        float cx = x1 + 0.5f * w + dx * w;
        float h2 = h * expf(dh);
        float w2 = w * expf(dw);
        float oy1 = fminf(fmaxf(cy - 0.5f * h2, 0.f), 1.f);
        float ox1 = fminf(fmaxf(cx - 0.5f * w2, 0.f), 1.f);
        float oy2 = fminf(fmaxf(cy + 0.5f * h2, 0.f), 1.f);
        float ox2 = fminf(fmaxf(cx + 0.5f * w2, 0.f), 1.f);
        bool valid = (bi > 0) && (bv >= kMinConf);
        float kv = valid ? bv : -INFINITY;
        float4 bx; bx.x = oy1; bx.y = ox1; bx.z = oy2; bx.w = ox2;
        ((float4*)boxes)[wid] = bx;
        key[wid] = kv;
        cls[wid] = bi;
        unsigned int i_in_b = (unsigned int)(wid % NN);
        ckey[wid] = ((unsigned long long)mono_u32(kv) << 32) | (unsigned int)(~i_in_b);
    }
}

// ---- k2: LDS-staged rank sort. Block = 64 i's, 4 waves each counting a
// 500-j quarter over the batch's u64 keys staged in LDS (uniform-address
// reads broadcast). rank(i) = #{j : K[j] > K[i]} == stable descending sort.
__global__ void __launch_bounds__(256) k2_rank(
                        const float* __restrict__ boxes,
                        const float* __restrict__ key,
                        const int* __restrict__ cls,
                        const unsigned long long* __restrict__ ckey,
                        float* __restrict__ sboxes,
                        float* __restrict__ sscore,
                        int* __restrict__ scls) {
    __shared__ ulonglong2 lk2[NN / 2];
    __shared__ int part[4][64];
    unsigned long long* lkey = (unsigned long long*)lk2;

    const int blk = blockIdx.x;
    const int b = blk >> 5;                 // 32 blocks per batch
    const int i0 = (blk & 31) * 64;         // 0..1984

    const ulonglong2* ck2 = (const ulonglong2*)(ckey + (size_t)b * NN);
    for (int t = threadIdx.x; t < NN / 2; t += 256) lk2[t] = ck2[t];
    __syncthreads();

    const int w = threadIdx.x >> 6;
    const int l = threadIdx.x & 63;
    const int i = i0 + l;
    const unsigned long long Ki = lkey[(i < NN) ? i : (NN - 1)];

    int r = 0;
    const int j0 = w * 500;
    #pragma unroll 4
    for (int j = j0; j < j0 + 500; ++j) r += (int)(lkey[j] > Ki);
    part[w][l] = r;
    __syncthreads();

    if (threadIdx.x < 64) {
        int i2 = i0 + threadIdx.x;
        if (i2 < NN) {
            int rank = part[0][threadIdx.x] + part[1][threadIdx.x]
                     + part[2][threadIdx.x] + part[3][threadIdx.x];
            int src = b * NN + i2;
            int dst = b * NN + rank;
            ((float4*)sboxes)[dst] = ((const float4*)boxes)[src];
            sscore[dst] = key[src];
            scls[dst] = cls[src];
        }
    }
}

__device__ __forceinline__ float iou_gt_thr(float4 a, float aarea, float4 t) {
    float iy1 = fmaxf(a.x, t.x), ix1 = fmaxf(a.y, t.y);
    float iy2 = fminf(a.z, t.z), ix2 = fminf(a.w, t.w);
    float inter = fmaxf(iy2 - iy1, 0.f) * fmaxf(ix2 - ix1, 0.f);
    float tarea = (t.z - t.x) * (t.w - t.y);
    float uni = fmaxf(aarea + tarea - inter, 1e-12f);
    return (inter > kNmsThr * uni) ? 1.f : 0.f;
}

// ---- k3: per-(batch,class) greedy NMS (exact decomposition by class) ----
__global__ void __launch_bounds__(64) k3_classnms(const float* __restrict__ sboxes,
                          const float* __restrict__ sscore,
                          const int* __restrict__ scls,
                          unsigned long long* __restrict__ kw) {
    const int blk = blockIdx.x;
    const int b = blk / (CC - 1);
    const int c = blk % (CC - 1) + 1;      // classes 1..80 (class 0 never valid)
    const int l = threadIdx.x;

    const float4* bxs = (const float4*)sboxes + (size_t)b * NN;
    const float* ss = sscore + (size_t)b * NN;
    const int* cl = scls + (size_t)b * NN;

    __shared__ int    midx[NN];
    __shared__ float4 mbox[NN];
    __shared__ unsigned char mkept[NN];

    // scan sorted rows, collect members of class c (double-buffered)
    int cnt = 0;
    float sc_cur = ss[l];
    int   cl_cur = cl[l];
    constexpr int NCH = (NN + 63) / 64;
    for (int ch = 0; ch < NCH; ++ch) {
        int i_nxt = (ch + 1) * 64 + l;
        float sc_nxt = 0.f; int cl_nxt = -1;
        if (ch + 1 < NCH && i_nxt < NN) { sc_nxt = ss[i_nxt]; cl_nxt = cl[i_nxt]; }
        int i = ch * 64 + l;
        bool pred = (i < NN) && (cl_cur == c) && (sc_cur != -INFINITY);
        unsigned long long mask = __ballot(pred);
        if (pred) {
            int pos = cnt + __popcll(mask & ((1ull << l) - 1ull));
            midx[pos] = i;
            mbox[pos] = bxs[i];
        }
        cnt += __popcll(mask);
        sc_cur = sc_nxt; cl_cur = cl_nxt;
    }
    __syncthreads();

    // greedy NMS over members, 64 at a time, ballot fixpoint (== greedy)
    for (int q0 = 0; q0 < cnt; q0 += 64) {
        int m = q0 + l;
        bool active = (m < cnt);
        float4 a = mbox[active ? m : 0];
        float aarea = (a.z - a.x) * (a.w - a.y);

        bool presup = false;
        for (int t = 0; t < q0; ++t) {
            if (mkept[t] && iou_gt_thr(a, aarea, mbox[t]) != 0.f) presup = true;
        }

        unsigned long long colmask = 0ull;
        int tend = min(64, cnt - q0);
        for (int t = 0; t < tend; ++t) {
            float4 tb = mbox[q0 + t];
            if (t < l && iou_gt_thr(a, aarea, tb) != 0.f) colmask |= (1ull << t);
        }

        bool pre = active && !presup;
        unsigned long long kept = __ballot(pre);
        while (true) {
            bool alive0 = pre && ((colmask & kept) == 0ull);
            unsigned long long k2m = __ballot(alive0);
            if (k2m == kept) break;
            kept = k2m;
        }
        bool alive = pre && ((colmask & kept) == 0ull);
        if (active) {
            mkept[m] = alive ? 1 : 0;
            if (alive) {
                int j = midx[m];
                atomicOr(&kw[b * WPB + (j >> 6)], 1ull << (j & 63));
            }
        }
        __syncthreads();
    }
}

// ---- k4: emit first 100 kept rows in sorted order ----
__global__ void __launch_bounds__(64) k4_emit(const unsigned long long* __restrict__ kw,
                        const float* __restrict__ sboxes,
                        const float* __restrict__ sscore,
                        const int* __restrict__ scls,
                        float* __restrict__ out) {
    const int b = blockIdx.x;
    const int l = threadIdx.x;

    unsigned long long keep = (l < WPB) ? kw[b * WPB + l] : 0ull;

    int cnt = __popcll(keep);
    int base = 0, total = 0;
    for (int w2 = 0; w2 < 32; ++w2) {
        int c2 = __shfl(cnt, w2);
        if (w2 < l) base += c2;
        total += c2;
    }

    if (l < 32) {
        unsigned long long kk = keep;
        int r = base;
        while (kk) {
            int k = __builtin_ctzll(kk);
            kk &= kk - 1;
            if (r < MAXI) {
                int j = l * 64 + k;
                float4 bx = ((const float4*)sboxes)[b * NN + j];
                float* o = out + ((size_t)b * MAXI + r) * 6;
                o[0] = bx.x; o[1] = bx.y; o[2] = bx.z; o[3] = bx.w;
                o[4] = (float)scls[b * NN + j];
                o[5] = sscore[b * NN + j];
            }
            ++r;
        }
    }
    for (int r = total + l; r < MAXI; r += 64) {
        float* o = out + ((size_t)b * MAXI + r) * 6;
        #pragma unroll
        for (int q = 0; q < 6; ++q) o[q] = 0.f;
    }
}

extern "C" void kernel_launch(void* const* d_in, const int* in_sizes, int n_in,
                              void* d_out, int out_size, void* d_ws, size_t ws_size,
                              hipStream_t stream) {
    const float* rois   = (const float*)d_in[0];
    const float* probs  = (const float*)d_in[1];
    const float* deltas = (const float*)d_in[2];
    float* out = (float*)d_out;

    char* ws = (char*)d_ws;
    float* boxes  = (float*)(ws + 0);
    float* key    = (float*)(ws + 256000);
    int*   cls    = (int*)  (ws + 320000);
    float* sboxes = (float*)(ws + 384000);
    float* sscore = (float*)(ws + 640000);
    int*   scls   = (int*)  (ws + 704000);
    unsigned long long* kw   = (unsigned long long*)(ws + 768000);
    unsigned long long* ckey = (unsigned long long*)(ws + 770048);

    {
        int blocks = (BB * NN * 64) / 256;   // one wave per ROI
        k1_refine<<<blocks, 256, 0, stream>>>(rois, probs, deltas, boxes, key, cls, ckey, kw);
    }
    {
        k2_rank<<<BB * 32, 256, 0, stream>>>(boxes, key, cls, ckey, sboxes, sscore, scls);
    }
    {
        k3_classnms<<<BB * (CC - 1), 64, 0, stream>>>(sboxes, sscore, scls, kw);
    }
    {
        k4_emit<<<BB, 64, 0, stream>>>(kw, sboxes, sscore, scls, out);
    }
}